// Round 1
// baseline (325.786 us; speedup 1.0000x reference)
//
#include <hip/hip_runtime.h>
#include <hip/hip_bf16.h>
#include <math.h>

#define NH 8
#define HD 32
#define SEQ 2048
#define NB 4
#define DM 256
#define SCALE 0.17677669529663687f   // 1/sqrt(32)

typedef float f32x4 __attribute__((ext_vector_type(4)));
typedef __bf16 bf16x8 __attribute__((ext_vector_type(8)));

// ---------------- fold table: 64 derived 32-vectors ----------------
// v=0: t[64]  (coef max(0,j-31))
// v=1: t[0]   (coef max(0,2016-j))
// v=2..32:  SUF_m = sum_{r=m}^{31} t[r+32],  m=v-1   (edge j=v-2, j<=30)
// v=33..63: PRE_m = sum_{r=-31}^{m} t[r+32], m=v-64  (edge j=2017+(v-33))
__global__ void k_fold_table(const float* __restrict__ tbl, float* __restrict__ tfold) {
  int t = blockIdx.x * 256 + threadIdx.x;
  if (t >= 64 * HD) return;
  int v = t >> 5;
  int d = t & 31;
  float acc;
  if (v == 0) acc = tbl[64 * HD + d];
  else if (v == 1) acc = tbl[d];
  else if (v <= 32) {
    acc = 0.f;
    for (int r = v - 1; r <= 31; ++r) acc += tbl[(r + 32) * HD + d];
  } else {
    acc = 0.f;
    for (int r = -31; r <= v - 64; ++r) acc += tbl[(r + 32) * HD + d];
  }
  tfold[t] = acc;
}

// ---------------- per-row rel coefficients (f32 exact) ----------------
__global__ void k_rel_rows(const float* __restrict__ Qf, const float* __restrict__ tfold,
                           float* __restrict__ REL, float* __restrict__ EDGE) {
  int wid = threadIdx.x >> 6;
  int v = threadIdx.x & 63;
  int row = blockIdx.x * 4 + wid;
  const float* q = Qf + (size_t)row * HD;
  const float* tv = tfold + v * HD;
  float acc = 0.f;
#pragma unroll
  for (int d = 0; d < HD; ++d) acc = fmaf(q[d], tv[d], acc);
  if (v < 2) REL[(size_t)row * 2 + v] = acc;
  else EDGE[(size_t)row * 62 + (v - 2)] = acc;
}

// ---------------- f32 QKV projection GEMM, 128x128 tile ----------------
__launch_bounds__(256)
__global__ void k_gemm_qkv(const float* __restrict__ X,
                           const float* __restrict__ Wq, const float* __restrict__ Wk,
                           const float* __restrict__ Wv,
                           const float* __restrict__ bq, const float* __restrict__ bk,
                           const float* __restrict__ bv,
                           float* __restrict__ Qf, __bf16* __restrict__ Qb,
                           __bf16* __restrict__ Kb, __bf16* __restrict__ Vb) {
  const int mb = blockIdx.x, nb = blockIdx.y;
  const int which = nb >> 1;                       // 0=Q 1=K 2=V
  const float* W = which == 0 ? Wq : (which == 1 ? Wk : Wv);
  const float* bias = which == 0 ? bq : (which == 1 ? bk : bv);
  const int ncol0 = (nb & 1) * 128;
  const int mrow0 = mb * 128;
  __shared__ float As[8][128];
  __shared__ float Bs[8][128];
  const int tx = threadIdx.x & 15, ty = threadIdx.x >> 4;
  float acc[8][8] = {};
  for (int k0 = 0; k0 < DM; k0 += 8) {
    int rr = threadIdx.x >> 1, kk = (threadIdx.x & 1) * 4;
    float4 av = *(const float4*)(X + (size_t)(mrow0 + rr) * DM + k0 + kk);
    int kb = threadIdx.x >> 5, cc = (threadIdx.x & 31) * 4;
    float4 bv4 = *(const float4*)(W + (size_t)(k0 + kb) * DM + ncol0 + cc);
    __syncthreads();
    As[kk + 0][rr] = av.x; As[kk + 1][rr] = av.y;
    As[kk + 2][rr] = av.z; As[kk + 3][rr] = av.w;
    *(float4*)&Bs[kb][cc] = bv4;
    __syncthreads();
#pragma unroll
    for (int k = 0; k < 8; ++k) {
      float a[8], bb[8];
#pragma unroll
      for (int i = 0; i < 8; ++i) a[i] = As[k][i * 16 + ty];
#pragma unroll
      for (int j = 0; j < 8; ++j) bb[j] = Bs[k][j * 16 + tx];
#pragma unroll
      for (int i = 0; i < 8; ++i)
#pragma unroll
        for (int j = 0; j < 8; ++j)
          acc[i][j] = fmaf(a[i], bb[j], acc[i][j]);
    }
  }
#pragma unroll
  for (int i = 0; i < 8; ++i) {
    int r = mrow0 + i * 16 + ty;
    int bidx = r >> 11, s = r & 2047;
#pragma unroll
    for (int j = 0; j < 8; ++j) {
      int n = ncol0 + j * 16 + tx;           // 0..255 within this W
      int h = n >> 5, dh = n & 31;
      size_t idx = ((size_t)(bidx * NH + h) * SEQ + s) * HD + dh;
      float v = acc[i][j] + bias[n];
      if (which == 0) { Qf[idx] = v; Qb[idx] = (__bf16)(v * SCALE); }
      else if (which == 1) Kb[idx] = (__bf16)v;
      else Vb[idx] = (__bf16)v;
    }
  }
}

// ---------------- flash attention core ----------------
// block = 256 thr (4 waves), 64 q-rows per block, 64-wide j tiles
__launch_bounds__(256)
__global__ void k_flash(const __bf16* __restrict__ Qb, const __bf16* __restrict__ Kb,
                        const __bf16* __restrict__ Vb,
                        const float* __restrict__ REL, const float* __restrict__ EDGE,
                        const float* __restrict__ mask, float* __restrict__ Of) {
  const int bh = blockIdx.y;          // 0..31  (b*8+h)
  const int qt = blockIdx.x;          // 0..31
  const int b = bh >> 3;
  const int tid = threadIdx.x;
  const int wid = tid >> 6, lane = tid & 63;
  const int l16 = lane & 15, lhi = lane >> 4;

  __shared__ __align__(16) __bf16 klds[64][40];   // pad: 80B rows (16B-mult)
  __shared__ __align__(16) __bf16 vlds[32][72];   // V transposed [d][j], 144B rows
  __shared__ __align__(16) __bf16 plds[4][16][72];

  const int qrow0 = qt * 64;
  const size_t rowg0 = (size_t)bh * SEQ + qrow0;

  float uu[4], ww[4];
#pragma unroll
  for (int r = 0; r < 4; ++r) {
    size_t rg = rowg0 + wid * 16 + lhi * 4 + r;
    uu[r] = REL[rg * 2];
    ww[r] = REL[rg * 2 + 1];
  }

  bf16x8 qfrag = *(const bf16x8*)(Qb + (rowg0 + wid * 16 + l16) * HD + lhi * 8);

  f32x4 of0 = {0.f, 0.f, 0.f, 0.f}, of1 = {0.f, 0.f, 0.f, 0.f};
  const f32x4 zero4 = {0.f, 0.f, 0.f, 0.f};
  float mrow[4] = {-INFINITY, -INFINITY, -INFINITY, -INFINITY};
  float lrow[4] = {0.f, 0.f, 0.f, 0.f};

  for (int jb = 0; jb < SEQ; jb += 64) {
    {   // stage K tile and transposed V tile
      int ch = tid & 3, j = tid >> 2;
      bf16x8 kv = *(const bf16x8*)(Kb + ((size_t)bh * SEQ + jb + j) * HD + ch * 8);
      *(bf16x8*)&klds[j][ch * 8] = kv;
      bf16x8 vv = *(const bf16x8*)(Vb + ((size_t)bh * SEQ + jb + j) * HD + ch * 8);
#pragma unroll
      for (int e = 0; e < 8; ++e) vlds[ch * 8 + e][j] = vv[e];
    }
    __syncthreads();

    f32x4 sf[4];
#pragma unroll
    for (int jt = 0; jt < 4; ++jt) {
      bf16x8 kf = *(const bf16x8*)&klds[jt * 16 + l16][lhi * 8];
      sf[jt] = __builtin_amdgcn_mfma_f32_16x16x32_bf16(qfrag, kf, zero4, 0, 0, 0);
    }

    float sv[4][4];
    float tmax[4] = {-INFINITY, -INFINITY, -INFINITY, -INFINITY};
#pragma unroll
    for (int jt = 0; jt < 4; ++jt) {
      int j = jb + jt * 16 + l16;
      float aj = (float)((j - 31) > 0 ? (j - 31) : 0);
      float bj = (float)((2016 - j) > 0 ? (2016 - j) : 0);
      float mterm = (1.0f - mask[(size_t)b * SEQ + j]) * -1e9f;
#pragma unroll
      for (int r = 0; r < 4; ++r) {
        float s = sf[jt][r] + aj * uu[r] + bj * ww[r] + mterm;
        if (j <= 30)
          s -= EDGE[(rowg0 + wid * 16 + lhi * 4 + r) * 62 + j];
        else if (j >= 2017)
          s -= EDGE[(rowg0 + wid * 16 + lhi * 4 + r) * 62 + 31 + (j - 2017)];
        sv[jt][r] = s;
        tmax[r] = fmaxf(tmax[r], s);
      }
    }
#pragma unroll
    for (int off = 1; off < 16; off <<= 1)
#pragma unroll
      for (int r = 0; r < 4; ++r)
        tmax[r] = fmaxf(tmax[r], __shfl_xor(tmax[r], off));

    float csum[4];
#pragma unroll
    for (int r = 0; r < 4; ++r) {
      float mn = fmaxf(mrow[r], tmax[r]);
      float c = __expf(mrow[r] - mn);   // exp(-inf)=0 on first tile
      mrow[r] = mn;
      lrow[r] *= c;
      of0[r] *= c; of1[r] *= c;
      csum[r] = 0.f;
    }
#pragma unroll
    for (int jt = 0; jt < 4; ++jt)
#pragma unroll
      for (int r = 0; r < 4; ++r) {
        float p = __expf(sv[jt][r] - mrow[r]);
        csum[r] += p;
        plds[wid][lhi * 4 + r][jt * 16 + l16] = (__bf16)p;
      }
#pragma unroll
    for (int off = 1; off < 16; off <<= 1)
#pragma unroll
      for (int r = 0; r < 4; ++r)
        csum[r] += __shfl_xor(csum[r], off);
#pragma unroll
    for (int r = 0; r < 4; ++r) lrow[r] += csum[r];

    // PV: O[i][d] += P[i][j] V[j][d]
#pragma unroll
    for (int kt = 0; kt < 2; ++kt) {
      bf16x8 pa = *(const bf16x8*)&plds[wid][l16][kt * 32 + lhi * 8];
      bf16x8 v0 = *(const bf16x8*)&vlds[l16][kt * 32 + lhi * 8];
      bf16x8 v1 = *(const bf16x8*)&vlds[16 + l16][kt * 32 + lhi * 8];
      of0 = __builtin_amdgcn_mfma_f32_16x16x32_bf16(pa, v0, of0, 0, 0, 0);
      of1 = __builtin_amdgcn_mfma_f32_16x16x32_bf16(pa, v1, of1, 0, 0, 0);
    }
    __syncthreads();
  }

#pragma unroll
  for (int r = 0; r < 4; ++r) {
    float inv = 1.0f / lrow[r];
    size_t rg = rowg0 + wid * 16 + lhi * 4 + r;
    Of[rg * HD + l16] = of0[r] * inv;
    Of[rg * HD + 16 + l16] = of1[r] * inv;
  }
}

// ---------------- f32 output projection GEMM ----------------
__launch_bounds__(256)
__global__ void k_gemm_out(const float* __restrict__ O, const float* __restrict__ Wo,
                           const float* __restrict__ bo, float* __restrict__ Y) {
  const int mb = blockIdx.x, nb = blockIdx.y;
  const int ncol0 = nb * 128, mrow0 = mb * 128;
  __shared__ float As[8][128];
  __shared__ float Bs[8][128];
  const int tx = threadIdx.x & 15, ty = threadIdx.x >> 4;
  float acc[8][8] = {};
  for (int k0 = 0; k0 < DM; k0 += 8) {
    int rr = threadIdx.x >> 1, kk = (threadIdx.x & 1) * 4;
    int r = mrow0 + rr;
    int bidx = r >> 11, s = r & 2047;
    int k = k0 + kk, h = k >> 5, dh = k & 31;
    float4 av = *(const float4*)(O + ((size_t)(bidx * NH + h) * SEQ + s) * HD + dh);
    int kb = threadIdx.x >> 5, cc = (threadIdx.x & 31) * 4;
    float4 bv4 = *(const float4*)(Wo + (size_t)(k0 + kb) * DM + ncol0 + cc);
    __syncthreads();
    As[kk + 0][rr] = av.x; As[kk + 1][rr] = av.y;
    As[kk + 2][rr] = av.z; As[kk + 3][rr] = av.w;
    *(float4*)&Bs[kb][cc] = bv4;
    __syncthreads();
#pragma unroll
    for (int k2 = 0; k2 < 8; ++k2) {
      float a[8], bb[8];
#pragma unroll
      for (int i = 0; i < 8; ++i) a[i] = As[k2][i * 16 + ty];
#pragma unroll
      for (int j = 0; j < 8; ++j) bb[j] = Bs[k2][j * 16 + tx];
#pragma unroll
      for (int i = 0; i < 8; ++i)
#pragma unroll
        for (int j = 0; j < 8; ++j)
          acc[i][j] = fmaf(a[i], bb[j], acc[i][j]);
    }
  }
#pragma unroll
  for (int i = 0; i < 8; ++i) {
    int r = mrow0 + i * 16 + ty;
#pragma unroll
    for (int j = 0; j < 8; ++j) {
      int n = ncol0 + j * 16 + tx;
      Y[(size_t)r * DM + n] = acc[i][j] + bo[n];
    }
  }
}

extern "C" void kernel_launch(void* const* d_in, const int* in_sizes, int n_in,
                              void* d_out, int out_size, void* d_ws, size_t ws_size,
                              hipStream_t stream) {
  (void)in_sizes; (void)n_in; (void)out_size; (void)ws_size;
  const float* query = (const float*)d_in[0];
  const float* mask  = (const float*)d_in[1];
  const float* Wq = (const float*)d_in[2];
  const float* bq = (const float*)d_in[3];
  const float* Wk = (const float*)d_in[4];
  const float* bk = (const float*)d_in[5];
  const float* Wv = (const float*)d_in[6];
  const float* bv = (const float*)d_in[7];
  const float* Wo = (const float*)d_in[8];
  const float* bo = (const float*)d_in[9];
  const float* tbl = (const float*)d_in[10];
  float* out = (float*)d_out;
  char* ws = (char*)d_ws;

  // workspace layout (bytes):
  float*  Qf   = (float*)(ws);                          //  0 .. 8M    f32 Q [B,H,S,32]
  float*  Of   = (float*)(ws + 8ull  * 1024 * 1024);    //  8 .. 16M   f32 attn out
  float*  EDGE = (float*)(ws + 16ull * 1024 * 1024);    // 16 .. 32.3M [65536][62]
  float*  REL  = (float*)(ws + 33ull * 1024 * 1024);    // 33 .. 33.5M [65536][2]
  float*  TF   = (float*)(ws + 34ull * 1024 * 1024);    // 34M + 8KB
  __bf16* Qb   = (__bf16*)(ws + 35ull * 1024 * 1024);   // 35 .. 39M
  __bf16* Kb   = (__bf16*)(ws + 39ull * 1024 * 1024);   // 39 .. 43M
  __bf16* Vb   = (__bf16*)(ws + 43ull * 1024 * 1024);   // 43 .. 47M

  k_fold_table<<<8, 256, 0, stream>>>(tbl, TF);
  k_gemm_qkv<<<dim3(64, 6), 256, 0, stream>>>(query, Wq, Wk, Wv, bq, bk, bv,
                                              Qf, Qb, Kb, Vb);
  k_rel_rows<<<16384, 256, 0, stream>>>(Qf, TF, REL, EDGE);
  k_flash<<<dim3(32, 32), 256, 0, stream>>>(Qb, Kb, Vb, REL, EDGE, mask, Of);
  k_gemm_out<<<dim3(64, 2), 256, 0, stream>>>(Of, Wo, bo, out);
}

// Round 2
// 133.048 us; speedup vs baseline: 2.4486x; 2.4486x over previous
//
#include <hip/hip_runtime.h>
#include <hip/hip_bf16.h>
#include <math.h>

#define NH 8
#define HD 32
#define SEQ 2048
#define DM 256
#define SCALE 0.17677669529663687f      // 1/sqrt(32)
#define INV_SCALE 5.656854249492381f    // sqrt(32)

typedef float f32x4 __attribute__((ext_vector_type(4)));
typedef __bf16 bf16x8 __attribute__((ext_vector_type(8)));

#define GLOAD(g, l) __builtin_amdgcn_global_load_lds( \
    (const __attribute__((address_space(1))) void*)(g), \
    (__attribute__((address_space(3))) void*)(l), 16, 0, 0)

// ============ prep A: X->bf16, W transposes->bf16, MT/AJ/BJ, tfold ============
__global__ void k_prepA(const float* __restrict__ query, const float* __restrict__ mask,
                        const float* __restrict__ Wq, const float* __restrict__ Wk,
                        const float* __restrict__ Wv, const float* __restrict__ Wo,
                        const float* __restrict__ tbl,
                        __bf16* __restrict__ Xb, __bf16* __restrict__ Wt,
                        __bf16* __restrict__ WoT,
                        float* __restrict__ MT, float* __restrict__ AJ,
                        float* __restrict__ BJ, float* __restrict__ tfold) {
  const int blk = blockIdx.x, tid = threadIdx.x;
  if (blk < 1024) {                      // convert X (f32 -> bf16), 8 elems/thread
    size_t i = (size_t)blk * 2048 + (size_t)tid * 8;
    float4 a = *(const float4*)(query + i);
    float4 b4 = *(const float4*)(query + i + 4);
    union { __bf16 h[8]; bf16x8 v; } o;
    o.h[0] = (__bf16)a.x;  o.h[1] = (__bf16)a.y;
    o.h[2] = (__bf16)a.z;  o.h[3] = (__bf16)a.w;
    o.h[4] = (__bf16)b4.x; o.h[5] = (__bf16)b4.y;
    o.h[6] = (__bf16)b4.z; o.h[7] = (__bf16)b4.w;
    *(bf16x8*)(Xb + i) = o.v;
  } else if (blk < 1120) {               // Wt[768][256] = concat(Wq,Wk,Wv)^T bf16
    int tg = (blk - 1024) * 256 + tid;   // 0..24575
    int n = tg >> 5, kc = tg & 31;
    int which = n >> 8, nw = n & 255;
    const float* W = which == 0 ? Wq : (which == 1 ? Wk : Wv);
#pragma unroll
    for (int i = 0; i < 8; ++i)
      Wt[(size_t)n * 256 + kc * 8 + i] = (__bf16)W[(size_t)(kc * 8 + i) * 256 + nw];
  } else if (blk < 1152) {               // WoT[256][256] = Wo^T bf16
    int tg = (blk - 1120) * 256 + tid;   // 0..8191
    int n = tg >> 5, kc = tg & 31;
#pragma unroll
    for (int i = 0; i < 8; ++i)
      WoT[(size_t)n * 256 + kc * 8 + i] = (__bf16)Wo[(size_t)(kc * 8 + i) * 256 + n];
  } else if (blk == 1152) {              // MT, AJ, BJ tables
    for (int i = tid; i < 4 * SEQ; i += 256) MT[i] = (1.0f - mask[i]) * -1e9f;
    for (int j = tid; j < SEQ; j += 256) {
      int aj = j - 31;     AJ[j] = (float)(aj > 0 ? aj : 0);
      int bj = 2016 - j;   BJ[j] = (float)(bj > 0 ? bj : 0);
    }
  } else {                               // tfold[64][32]
    for (int t = tid; t < 2048; t += 256) {
      int v = t >> 5, d = t & 31;
      float acc;
      if (v == 0) acc = tbl[64 * HD + d];
      else if (v == 1) acc = tbl[d];
      else if (v <= 32) {
        acc = 0.f;
        for (int r = v - 1; r <= 31; ++r) acc += tbl[(r + 32) * HD + d];
      } else {
        acc = 0.f;
        for (int r = -31; r <= v - 64; ++r) acc += tbl[(r + 32) * HD + d];
      }
      tfold[t] = acc;
    }
  }
}

// ============ prep B: WV2 (f32), SUF/PRE bf16 tables, cb ============
__global__ void k_prepB(const float* __restrict__ Wq, const float* __restrict__ bq,
                        const float* __restrict__ tfold,
                        __bf16* __restrict__ SUFtab, __bf16* __restrict__ PREtab,
                        float* __restrict__ WV2, float* __restrict__ cb) {
  const int blk = blockIdx.x, tid = threadIdx.x;
  if (blk < 16) {                        // WV2[256][16]: col h*2+v = Wq[:,hslice]@t_v
    int tg = blk * 256 + tid;
    int k = tg >> 4, hv = tg & 15, h = hv >> 1, v = hv & 1;
    float acc = 0.f;
#pragma unroll
    for (int d = 0; d < 32; ++d)
      acc = fmaf(Wq[(size_t)k * 256 + h * 32 + d], tfold[v * 32 + d], acc);
    WV2[k * 16 + hv] = acc;
  } else if (blk < 24) {                 // SUF/PRE tables (pre-divided by SCALE)
    int tg = (blk - 16) * 256 + tid;     // 0..2047
    if (tg < 1024) {
      int j = tg >> 5, d = tg & 31;
      SUFtab[tg] = (__bf16)((j < 31) ? tfold[(j + 2) * 32 + d] * INV_SCALE : 0.f);
    } else {
      int t2 = tg - 1024;
      int jj = t2 >> 5, d = t2 & 31;
      PREtab[t2] = (__bf16)((jj > 0) ? tfold[(32 + jj) * 32 + d] * INV_SCALE : 0.f);
    }
  } else {                               // cb[16] = bq[hslice]·t_v
    if (tid < 16) {
      int h = tid >> 1, v = tid & 1;
      float a = 0.f;
#pragma unroll
      for (int d = 0; d < 32; ++d) a = fmaf(bq[h * 32 + d], tfold[v * 32 + d], a);
      cb[tid] = a;
    }
  }
}

// ============ REL = X @ WV2 + cb   (f32 exact; big coefficients) ============
__launch_bounds__(256)
__global__ void k_rel(const float* __restrict__ X, const float* __restrict__ WV2,
                      const float* __restrict__ cb, float* __restrict__ REL) {
  const int tid = threadIdx.x;
  const int hv = tid & 15, rl = tid >> 4;
  const int row = blockIdx.x * 16 + rl;
  const float* x = X + (size_t)row * 256;
  float acc = cb[hv];
#pragma unroll 8
  for (int k = 0; k < 256; k += 4) {
    float4 xv = *(const float4*)(x + k);
    acc = fmaf(xv.x, WV2[(k + 0) * 16 + hv], acc);
    acc = fmaf(xv.y, WV2[(k + 1) * 16 + hv], acc);
    acc = fmaf(xv.z, WV2[(k + 2) * 16 + hv], acc);
    acc = fmaf(xv.w, WV2[(k + 3) * 16 + hv], acc);
  }
  int b = row >> 11, s = row & 2047, h = hv >> 1, v = hv & 1;
  REL[((size_t)(b * NH + h) * SEQ + s) * 2 + v] = acc;
}

// ============ bf16 MFMA GEMM (MODE 0: X@[Wq|Wk|Wv] -> Qb,Kb,Vb; MODE 1: Ob@Wo -> Y) ============
template <int MODE>
__launch_bounds__(256)
__global__ void k_gemm(const __bf16* __restrict__ A, const __bf16* __restrict__ Bt,
                       const float* __restrict__ b0, const float* __restrict__ b1,
                       const float* __restrict__ b2,
                       __bf16* __restrict__ Qb, __bf16* __restrict__ Kb,
                       __bf16* __restrict__ Vb, float* __restrict__ Y) {
  constexpr int BN = (MODE == 0) ? 128 : 64;
  constexpr int NFJ = BN / 32;
  __shared__ __align__(16) __bf16 As[128 * 64];
  __shared__ __align__(16) __bf16 Bs[BN * 64];
  const int tid = threadIdx.x, lane = tid & 63, wid = tid >> 6;
  const int l16 = lane & 15, lhi = lane >> 4;
  const int wr = wid >> 1, wc = wid & 1;
  const int m0 = blockIdx.x * 128, n0 = blockIdx.y * BN;

  f32x4 acc[4][NFJ];
#pragma unroll
  for (int i = 0; i < 4; ++i)
#pragma unroll
    for (int j = 0; j < NFJ; ++j) acc[i][j] = (f32x4){0.f, 0.f, 0.f, 0.f};

  for (int k0 = 0; k0 < 256; k0 += 64) {
    __syncthreads();
    // stage A tile [128][64] swizzled
#pragma unroll
    for (int cc = 0; cc < 4; ++cc) {
      int cl = tid + cc * 256;
      int row = cl >> 3, kc = cl & 7;
      int k = k0 + ((kc ^ (row & 7)) * 8);
      const __bf16* src;
      if constexpr (MODE == 0) {
        src = A + (size_t)(m0 + row) * 256 + k;
      } else {
        int r = m0 + row, bb = r >> 11, s = r & 2047, h = k >> 5, dh = k & 31;
        src = A + ((size_t)(bb * NH + h) * SEQ + s) * HD + dh;
      }
      GLOAD(src, (__bf16*)As + (size_t)cl * 8);
    }
    // stage B tile [BN][64] swizzled
#pragma unroll
    for (int cc = 0; cc < NFJ; ++cc) {
      int cl = tid + cc * 256;
      int row = cl >> 3, kc = cl & 7;
      int k = k0 + ((kc ^ (row & 7)) * 8);
      GLOAD(Bt + (size_t)(n0 + row) * 256 + k, (__bf16*)Bs + (size_t)cl * 8);
    }
    __syncthreads();
#pragma unroll
    for (int kk = 0; kk < 64; kk += 32) {
      bf16x8 af[4], bf[NFJ];
#pragma unroll
      for (int fi = 0; fi < 4; ++fi) {
        int row = wr * 64 + fi * 16 + l16;
        af[fi] = *(const bf16x8*)(As + row * 64 + ((((kk >> 3) + lhi) ^ (row & 7)) * 8));
      }
#pragma unroll
      for (int fj = 0; fj < NFJ; ++fj) {
        int row = wc * (BN / 2) + fj * 16 + l16;
        bf[fj] = *(const bf16x8*)(Bs + row * 64 + ((((kk >> 3) + lhi) ^ (row & 7)) * 8));
      }
#pragma unroll
      for (int fi = 0; fi < 4; ++fi)
#pragma unroll
        for (int fj = 0; fj < NFJ; ++fj)
          acc[fi][fj] = __builtin_amdgcn_mfma_f32_16x16x32_bf16(af[fi], bf[fj], acc[fi][fj], 0, 0, 0);
    }
  }
  // epilogue
#pragma unroll
  for (int fi = 0; fi < 4; ++fi) {
#pragma unroll
    for (int fj = 0; fj < NFJ; ++fj) {
      int mrow = m0 + wr * 64 + fi * 16 + lhi * 4;
      int ncol = n0 + wc * (BN / 2) + fj * 16 + l16;
      if constexpr (MODE == 0) {
        int which = ncol >> 8, nw = ncol & 255, h = nw >> 5, dh = nw & 31;
        const float* bias = which == 0 ? b0 : (which == 1 ? b1 : b2);
#pragma unroll
        for (int r = 0; r < 4; ++r) {
          int row = mrow + r, bb = row >> 11, s = row & 2047;
          float v = acc[fi][fj][r] + bias[nw];
          size_t oi = ((size_t)(bb * NH + h) * SEQ + s) * HD + dh;
          if (which == 0) Qb[oi] = (__bf16)(v * SCALE);
          else if (which == 1) Kb[oi] = (__bf16)v;
          else Vb[oi] = (__bf16)v;
        }
      } else {
#pragma unroll
        for (int r = 0; r < 4; ++r)
          Y[(size_t)(mrow + r) * 256 + ncol] = acc[fi][fj][r] + b0[ncol];
      }
    }
  }
}

// ============ V transpose: Vb[bh][s][d] -> VT[bh][d][s] ============
__global__ void k_vt(const __bf16* __restrict__ Vb, __bf16* __restrict__ VT) {
  __shared__ __bf16 t[64][40];
  const int bh = blockIdx.y, s0 = blockIdx.x * 64, tid = threadIdx.x;
  const int sl = tid >> 2, ch = tid & 3;
  bf16x8 v = *(const bf16x8*)(Vb + ((size_t)bh * SEQ + s0 + sl) * HD + ch * 8);
  *(bf16x8*)&t[sl][ch * 8] = v;
  __syncthreads();
  const int d = tid >> 3, c = tid & 7;
  union { __bf16 h[8]; bf16x8 v8; } o;
#pragma unroll
  for (int i = 0; i < 8; ++i) o.h[i] = t[c * 8 + i][d];
  *(bf16x8*)(VT + ((size_t)bh * HD + d) * SEQ + s0 + c * 8) = o.v8;
}

// ============ flash attention core (swapped-operand, dbuf global_load_lds) ============
__launch_bounds__(256)
__global__ void k_flash(const __bf16* __restrict__ Qb, const __bf16* __restrict__ Kb,
                        const __bf16* __restrict__ VT, const float* __restrict__ REL,
                        const __bf16* __restrict__ SUFtab, const __bf16* __restrict__ PREtab,
                        const float* __restrict__ MT, const float* __restrict__ AJ,
                        const float* __restrict__ BJ, __bf16* __restrict__ Ob) {
  const int bh = blockIdx.y, qt = blockIdx.x, b = bh >> 3;
  const int tid = threadIdx.x, wid = tid >> 6, lane = tid & 63;
  const int l16 = lane & 15, lhi = lane >> 4;

  __shared__ __align__(16) __bf16 kbuf[2][64 * 32];
  __shared__ __align__(16) __bf16 vbuf[2][32 * 64];
  __shared__ __align__(16) __bf16 plds[4][16 * 72];

  const int qrow = qt * 64 + wid * 16 + l16;
  const size_t rg = (size_t)bh * SEQ + qrow;

  const bf16x8 qfrag = *(const bf16x8*)(Qb + rg * HD + lhi * 8);
  const float uu = REL[rg * 2], ww = REL[rg * 2 + 1];
  const bf16x8 suf0 = *(const bf16x8*)(SUFtab + l16 * HD + lhi * 8);
  const bf16x8 suf1 = *(const bf16x8*)(SUFtab + (16 + l16) * HD + lhi * 8);
  const bf16x8 pre2 = *(const bf16x8*)(PREtab + l16 * HD + lhi * 8);
  const bf16x8 pre3 = *(const bf16x8*)(PREtab + (16 + l16) * HD + lhi * 8);

  // staging source/dest (swizzled global source, linear LDS dest)
  const int kj = tid >> 2, kc = tid & 3;
  const __bf16* ksrc = Kb + (size_t)bh * SEQ * HD + (size_t)kj * HD + ((kc ^ ((kj >> 1) & 3)) * 8);
  const int vd = tid >> 3, vc = tid & 7;
  const __bf16* vsrc = VT + ((size_t)bh * HD + vd) * SEQ + ((vc ^ (vd & 7)) * 8);
  __bf16* kdst0 = &kbuf[0][(size_t)tid * 8];
  __bf16* kdst1 = &kbuf[1][(size_t)tid * 8];
  __bf16* vdst0 = &vbuf[0][(size_t)tid * 8];
  __bf16* vdst1 = &vbuf[1][(size_t)tid * 8];

  f32x4 of0 = {0.f, 0.f, 0.f, 0.f}, of1 = {0.f, 0.f, 0.f, 0.f};
  const f32x4 zero4 = {0.f, 0.f, 0.f, 0.f};
  float m = -3.0e38f, lsum = 0.f;

  GLOAD(ksrc, kdst0);
  GLOAD(vsrc, vdst0);
  __syncthreads();

  __bf16* pl = &plds[wid][0];

  for (int jb = 0, cur = 0; jb < SEQ; jb += 64, cur ^= 1) {
    if (jb + 64 < SEQ) {                  // prefetch next tile into other buffer
      GLOAD(ksrc + (size_t)(jb + 64) * HD, cur ? kdst0 : kdst1);
      GLOAD(vsrc + (jb + 64), cur ? vdst0 : vdst1);
    }
    const __bf16* kb = kbuf[cur];
    const __bf16* vb = vbuf[cur];

    // QK^T (swapped: K as A, Q as B) -> lane holds S[q=l16][j=jb+jt*16+lhi*4+r]
    f32x4 sf[4];
#pragma unroll
    for (int jt = 0; jt < 4; ++jt) {
      int row = jt * 16 + l16;
      bf16x8 kf = *(const bf16x8*)(kb + row * 32 + ((lhi ^ ((row >> 1) & 3)) * 8));
      sf[jt] = __builtin_amdgcn_mfma_f32_16x16x32_bf16(kf, qfrag, zero4, 0, 0, 0);
    }
    if (jb == 0) {
      sf[0] -= __builtin_amdgcn_mfma_f32_16x16x32_bf16(suf0, qfrag, zero4, 0, 0, 0);
      sf[1] -= __builtin_amdgcn_mfma_f32_16x16x32_bf16(suf1, qfrag, zero4, 0, 0, 0);
    }
    if (jb == SEQ - 64) {
      sf[2] -= __builtin_amdgcn_mfma_f32_16x16x32_bf16(pre2, qfrag, zero4, 0, 0, 0);
      sf[3] -= __builtin_amdgcn_mfma_f32_16x16x32_bf16(pre3, qfrag, zero4, 0, 0, 0);
    }

    float p[4][4];
    float tmax = -3.0e38f;
#pragma unroll
    for (int jt = 0; jt < 4; ++jt) {
      int j0 = jb + jt * 16 + lhi * 4;
      f32x4 aj = *(const f32x4*)(AJ + j0);
      f32x4 bj = *(const f32x4*)(BJ + j0);
      f32x4 mt = *(const f32x4*)(MT + b * SEQ + j0);
#pragma unroll
      for (int r = 0; r < 4; ++r) {
        float s = sf[jt][r] + mt[r] + aj[r] * uu + bj[r] * ww;
        p[jt][r] = s;
        tmax = fmaxf(tmax, s);
      }
    }
    tmax = fmaxf(tmax, __shfl_xor(tmax, 16));
    tmax = fmaxf(tmax, __shfl_xor(tmax, 32));

    float mn = fmaxf(m, tmax);
    float c = __expf(m - mn);
    m = mn;
    float csum = 0.f;
#pragma unroll
    for (int jt = 0; jt < 4; ++jt)
#pragma unroll
      for (int r = 0; r < 4; ++r) {
        float e = __expf(p[jt][r] - m);
        p[jt][r] = e;
        csum += e;
      }
    csum += __shfl_xor(csum, 16);
    csum += __shfl_xor(csum, 32);
    lsum = lsum * c + csum;
    of0 *= c;
    of1 *= c;

    // P -> LDS (b64 writes), layout P[q=l16][jcol], pitch 72
#pragma unroll
    for (int jt = 0; jt < 4; ++jt) {
      union { __bf16 h[4]; uint2 u; } pk;
#pragma unroll
      for (int r = 0; r < 4; ++r) pk.h[r] = (__bf16)p[jt][r];
      *(uint2*)(pl + l16 * 72 + jt * 16 + lhi * 4) = pk.u;
    }

    // PV (swapped: V^T as A, P as B) -> of[r] = O[d=lhi*4+r][q=l16]
#pragma unroll
    for (int kt = 0; kt < 2; ++kt) {
      bf16x8 pf = *(const bf16x8*)(pl + l16 * 72 + kt * 32 + lhi * 8);
      int d1 = 16 + l16;
      bf16x8 v0 = *(const bf16x8*)(vb + l16 * 64 + (((kt * 4 + lhi) ^ (l16 & 7)) * 8));
      bf16x8 v1 = *(const bf16x8*)(vb + d1 * 64 + (((kt * 4 + lhi) ^ (d1 & 7)) * 8));
      of0 = __builtin_amdgcn_mfma_f32_16x16x32_bf16(v0, pf, of0, 0, 0, 0);
      of1 = __builtin_amdgcn_mfma_f32_16x16x32_bf16(v1, pf, of1, 0, 0, 0);
    }
    __syncthreads();
  }

  float inv = 1.0f / lsum;
  union { __bf16 h[4]; uint2 u; } o0, o1;
#pragma unroll
  for (int r = 0; r < 4; ++r) {
    o0.h[r] = (__bf16)(of0[r] * inv);
    o1.h[r] = (__bf16)(of1[r] * inv);
  }
  *(uint2*)(Ob + rg * HD + lhi * 4) = o0.u;
  *(uint2*)(Ob + rg * HD + 16 + lhi * 4) = o1.u;
}

// ============ launch ============
extern "C" void kernel_launch(void* const* d_in, const int* in_sizes, int n_in,
                              void* d_out, int out_size, void* d_ws, size_t ws_size,
                              hipStream_t stream) {
  (void)in_sizes; (void)n_in; (void)out_size; (void)ws_size;
  const float* query = (const float*)d_in[0];
  const float* mask  = (const float*)d_in[1];
  const float* Wq = (const float*)d_in[2];
  const float* bq = (const float*)d_in[3];
  const float* Wk = (const float*)d_in[4];
  const float* bk = (const float*)d_in[5];
  const float* Wv = (const float*)d_in[6];
  const float* bv = (const float*)d_in[7];
  const float* Wo = (const float*)d_in[8];
  const float* bo = (const float*)d_in[9];
  const float* tbl = (const float*)d_in[10];
  float* out = (float*)d_out;
  char* ws = (char*)d_ws;

  __bf16* Xb    = (__bf16*)(ws + 0);                    // 4 MB
  __bf16* Wt    = (__bf16*)(ws + (4ull << 20));         // 384 KB
  __bf16* WoT   = (__bf16*)(ws + (4ull << 20) + 393216);          // 128 KB
  float*  tfold = (float*) (ws + (4ull << 20) + 524288);          // 8 KB
  __bf16* SUFt  = (__bf16*)(ws + (4ull << 20) + 532480);          // 2 KB
  __bf16* PREt  = (__bf16*)(ws + (4ull << 20) + 534528);          // 2 KB
  float*  WV2   = (float*) (ws + (4ull << 20) + 536576);          // 16 KB
  float*  cb    = (float*) (ws + (4ull << 20) + 552960);          // 64 B
  float*  MT    = (float*) (ws + (4ull << 20) + 553024);          // 32 KB
  float*  AJ    = (float*) (ws + (4ull << 20) + 585792);          // 8 KB
  float*  BJ    = (float*) (ws + (4ull << 20) + 593984);          // 8 KB
  float*  REL   = (float*) (ws + (5ull << 20));                   // 512 KB
  __bf16* Qb    = (__bf16*)(ws + (6ull << 20));         // 4 MB
  __bf16* Kb    = (__bf16*)(ws + (10ull << 20));        // 4 MB
  __bf16* Vb    = (__bf16*)(ws + (14ull << 20));        // 4 MB
  __bf16* VT    = (__bf16*)(ws + (18ull << 20));        // 4 MB
  __bf16* Ob    = (__bf16*)(ws + (22ull << 20));        // 4 MB

  k_prepA<<<1154, 256, 0, stream>>>(query, mask, Wq, Wk, Wv, Wo, tbl,
                                    Xb, Wt, WoT, MT, AJ, BJ, tfold);
  k_prepB<<<25, 256, 0, stream>>>(Wq, bq, tfold, SUFt, PREt, WV2, cb);
  k_rel<<<512, 256, 0, stream>>>(query, WV2, cb, REL);
  k_gemm<0><<<dim3(64, 6), 256, 0, stream>>>(Xb, Wt, bq, bk, bv, Qb, Kb, Vb, nullptr);
  k_vt<<<dim3(32, 32), 256, 0, stream>>>(Vb, VT);
  k_flash<<<dim3(32, 32), 256, 0, stream>>>(Qb, Kb, VT, REL, SUFt, PREt, MT, AJ, BJ, Ob);
  k_gemm<1><<<dim3(64, 4), 256, 0, stream>>>(Ob, WoT, bo, nullptr, nullptr,
                                             nullptr, nullptr, nullptr, out);
}

// Round 3
// 107.355 us; speedup vs baseline: 3.0346x; 1.2393x over previous
//
#include <hip/hip_runtime.h>
#include <hip/hip_bf16.h>
#include <math.h>

#define NH 8
#define HD 32
#define SEQ 2048
#define DM 256
#define SCALE 0.17677669529663687f      // 1/sqrt(32)
#define INV_SCALE 5.656854249492381f    // sqrt(32)
#define LOG2E 1.4426950408889634f
#define QSC (SCALE * LOG2E)
#define MNEG (-1e9f * LOG2E)

typedef float f32x4 __attribute__((ext_vector_type(4)));
typedef __bf16 bf16x8 __attribute__((ext_vector_type(8)));

#define GLOAD(g, l) __builtin_amdgcn_global_load_lds( \
    (const __attribute__((address_space(1))) void*)(g), \
    (__attribute__((address_space(3))) void*)(l), 16, 0, 0)

// ============ prep (merged): X->bf16, W transposes, MT, SUF/PRE, WV2T, cb ============
__global__ void k_prep(const float* __restrict__ query, const float* __restrict__ mask,
                       const float* __restrict__ Wq, const float* __restrict__ Wk,
                       const float* __restrict__ Wv, const float* __restrict__ Wo,
                       const float* __restrict__ bq, const float* __restrict__ tbl,
                       __bf16* __restrict__ Xb, __bf16* __restrict__ Wt,
                       __bf16* __restrict__ WoT, float* __restrict__ MT,
                       __bf16* __restrict__ SUFtab, __bf16* __restrict__ PREtab,
                       float* __restrict__ WV2T, float* __restrict__ cb) {
  const int blk = blockIdx.x, tid = threadIdx.x;
  if (blk < 1024) {                      // X f32 -> bf16
    size_t i = (size_t)blk * 2048 + (size_t)tid * 8;
    float4 a = *(const float4*)(query + i);
    float4 b4 = *(const float4*)(query + i + 4);
    union { __bf16 h[8]; bf16x8 v; } o;
    o.h[0] = (__bf16)a.x;  o.h[1] = (__bf16)a.y;
    o.h[2] = (__bf16)a.z;  o.h[3] = (__bf16)a.w;
    o.h[4] = (__bf16)b4.x; o.h[5] = (__bf16)b4.y;
    o.h[6] = (__bf16)b4.z; o.h[7] = (__bf16)b4.w;
    *(bf16x8*)(Xb + i) = o.v;
  } else if (blk < 1120) {               // Wt[768][256] = concat(Wq,Wk,Wv)^T bf16
    int tg = (blk - 1024) * 256 + tid;
    int n = tg >> 5, kc = tg & 31;
    int which = n >> 8, nw = n & 255;
    const float* W = which == 0 ? Wq : (which == 1 ? Wk : Wv);
#pragma unroll
    for (int i = 0; i < 8; ++i)
      Wt[(size_t)n * 256 + kc * 8 + i] = (__bf16)W[(size_t)(kc * 8 + i) * 256 + nw];
  } else if (blk < 1152) {               // WoT[256][256] = Wo^T bf16
    int tg = (blk - 1120) * 256 + tid;
    int n = tg >> 5, kc = tg & 31;
#pragma unroll
    for (int i = 0; i < 8; ++i)
      WoT[(size_t)n * 256 + kc * 8 + i] = (__bf16)Wo[(size_t)(kc * 8 + i) * 256 + n];
  } else if (blk == 1152) {              // MT (log2e-folded mask term)
    for (int i = tid; i < 4 * SEQ; i += 256) MT[i] = (1.0f - mask[i]) * MNEG;
  } else if (blk == 1153) {              // SUF/PRE tables (prefix sums, /SCALE)
    for (int idx = tid; idx < 1024; idx += 256) {
      int j = idx >> 5, d = idx & 31;
      float s = 0.f;
      for (int u = j + 33; u <= 63; ++u) s += tbl[u * 32 + d];
      SUFtab[idx] = (__bf16)(s * INV_SCALE);
    }
    for (int idx = tid; idx < 1024; idx += 256) {
      int jj = idx >> 5, d = idx & 31;
      float s = 0.f;
      for (int u = 1; u <= jj; ++u) s += tbl[u * 32 + d];
      PREtab[idx] = (__bf16)(s * INV_SCALE);
    }
  } else if (blk < 1170) {               // WV2T[16][256] (x log2e)
    int tg = (blk - 1154) * 256 + tid;
    int hv = tg >> 8, k = tg & 255;
    const float* T = tbl + ((hv & 1) ? 0 : 64 * 32);
    const float* w = Wq + (size_t)k * 256 + (hv >> 1) * 32;
    float acc = 0.f;
#pragma unroll
    for (int d = 0; d < 32; ++d) acc = fmaf(w[d], T[d], acc);
    WV2T[hv * 256 + k] = acc * LOG2E;
  } else {                               // cb[16]
    if (tid < 16) {
      const float* T = tbl + ((tid & 1) ? 0 : 64 * 32);
      float a = 0.f;
#pragma unroll
      for (int d = 0; d < 32; ++d) a = fmaf(bq[(tid >> 1) * 32 + d], T[d], a);
      cb[tid] = a * LOG2E;
    }
  }
}

// ============ REL = (X @ WV2T^T + cb) * log2e  (f32 exact) ============
__launch_bounds__(256)
__global__ void k_rel(const float* __restrict__ X, const float* __restrict__ WV2T,
                      const float* __restrict__ cb, float* __restrict__ REL) {
  const int tid = threadIdx.x;
  const int hv = tid & 15, rl = tid >> 4;
  const int row0 = blockIdx.x * 32 + rl;
  const float* x0 = X + (size_t)row0 * 256;
  const float* x1 = x0 + 16 * 256;
  const float* wv = WV2T + hv * 256;
  float a0 = cb[hv], a1 = a0;
#pragma unroll 4
  for (int k = 0; k < 256; k += 4) {
    f32x4 w4 = *(const f32x4*)(wv + k);
    f32x4 xa = *(const f32x4*)(x0 + k);
    f32x4 xb = *(const f32x4*)(x1 + k);
    a0 = fmaf(xa.x, w4.x, a0); a0 = fmaf(xa.y, w4.y, a0);
    a0 = fmaf(xa.z, w4.z, a0); a0 = fmaf(xa.w, w4.w, a0);
    a1 = fmaf(xb.x, w4.x, a1); a1 = fmaf(xb.y, w4.y, a1);
    a1 = fmaf(xb.z, w4.z, a1); a1 = fmaf(xb.w, w4.w, a1);
  }
  const int h = hv >> 1, v = hv & 1;
  const int b0i = row0 >> 11, s0 = row0 & 2047;
  REL[((size_t)(b0i * NH + h) * SEQ + s0) * 2 + v] = a0;
  const int r1 = row0 + 16;
  const int b1i = r1 >> 11, s1 = r1 & 2047;
  REL[((size_t)(b1i * NH + h) * SEQ + s1) * 2 + v] = a1;
}

// ============ bf16 MFMA GEMM ============
// MODE 0: Xb@[Wq|Wk|Wv] -> Qb (x SCALE*log2e), Kb, VT (transposed write)
// MODE 1: Ob@Wo -> Y f32
template <int MODE>
__launch_bounds__(256)
__global__ void k_gemm(const __bf16* __restrict__ A, const __bf16* __restrict__ Bt,
                       const float* __restrict__ b0, const float* __restrict__ b1,
                       const float* __restrict__ b2,
                       __bf16* __restrict__ Qb, __bf16* __restrict__ Kb,
                       __bf16* __restrict__ VTout, float* __restrict__ Y) {
  constexpr int BN = (MODE == 0) ? 128 : 64;
  constexpr int NFJ = BN / 32;
  __shared__ __align__(16) __bf16 As[128 * 64];
  __shared__ __align__(16) __bf16 Bs[BN * 64];
  const int tid = threadIdx.x, lane = tid & 63, wid = tid >> 6;
  const int l16 = lane & 15, lhi = lane >> 4;
  const int wr = wid >> 1, wc = wid & 1;
  const int m0 = blockIdx.x * 128, n0 = blockIdx.y * BN;

  f32x4 acc[4][NFJ];
#pragma unroll
  for (int i = 0; i < 4; ++i)
#pragma unroll
    for (int j = 0; j < NFJ; ++j) acc[i][j] = (f32x4){0.f, 0.f, 0.f, 0.f};

  for (int k0 = 0; k0 < 256; k0 += 64) {
    __syncthreads();
#pragma unroll
    for (int cc = 0; cc < 4; ++cc) {
      int cl = tid + cc * 256;
      int row = cl >> 3, kc = cl & 7;
      int k = k0 + ((kc ^ (row & 7)) * 8);
      const __bf16* src;
      if constexpr (MODE == 0) {
        src = A + (size_t)(m0 + row) * 256 + k;
      } else {
        int r = m0 + row, bb = r >> 11, s = r & 2047, h = k >> 5, dh = k & 31;
        src = A + ((size_t)(bb * NH + h) * SEQ + s) * HD + dh;
      }
      GLOAD(src, (__bf16*)As + (size_t)cl * 8);
    }
#pragma unroll
    for (int cc = 0; cc < NFJ; ++cc) {
      int cl = tid + cc * 256;
      int row = cl >> 3, kc = cl & 7;
      int k = k0 + ((kc ^ (row & 7)) * 8);
      GLOAD(Bt + (size_t)(n0 + row) * 256 + k, (__bf16*)Bs + (size_t)cl * 8);
    }
    __syncthreads();
#pragma unroll
    for (int kk = 0; kk < 64; kk += 32) {
      bf16x8 af[4], bfr[NFJ];
#pragma unroll
      for (int fi = 0; fi < 4; ++fi) {
        int row = wr * 64 + fi * 16 + l16;
        af[fi] = *(const bf16x8*)(As + row * 64 + ((((kk >> 3) + lhi) ^ (row & 7)) * 8));
      }
#pragma unroll
      for (int fj = 0; fj < NFJ; ++fj) {
        int row = wc * (BN / 2) + fj * 16 + l16;
        bfr[fj] = *(const bf16x8*)(Bs + row * 64 + ((((kk >> 3) + lhi) ^ (row & 7)) * 8));
      }
#pragma unroll
      for (int fi = 0; fi < 4; ++fi)
#pragma unroll
        for (int fj = 0; fj < NFJ; ++fj)
          acc[fi][fj] = __builtin_amdgcn_mfma_f32_16x16x32_bf16(af[fi], bfr[fj], acc[fi][fj], 0, 0, 0);
    }
  }
#pragma unroll
  for (int fi = 0; fi < 4; ++fi) {
#pragma unroll
    for (int fj = 0; fj < NFJ; ++fj) {
      int mrow = m0 + wr * 64 + fi * 16 + lhi * 4;
      int ncol = n0 + wc * (BN / 2) + fj * 16 + l16;
      if constexpr (MODE == 0) {
        int which = ncol >> 8, nw = ncol & 255, h = nw >> 5, dh = nw & 31;
        int bb = mrow >> 11, s0 = mrow & 2047;
        if (which == 2) {
          union { __bf16 h4[4]; uint2 u; } o;
#pragma unroll
          for (int r = 0; r < 4; ++r) o.h4[r] = (__bf16)(acc[fi][fj][r] + b2[nw]);
          *(uint2*)(VTout + ((size_t)(bb * NH + h) * HD + dh) * SEQ + s0) = o.u;
        } else {
          const float* bias = which == 0 ? b0 : b1;
#pragma unroll
          for (int r = 0; r < 4; ++r) {
            float v = acc[fi][fj][r] + bias[nw];
            size_t oi = ((size_t)(bb * NH + h) * SEQ + (s0 + r)) * HD + dh;
            if (which == 0) Qb[oi] = (__bf16)(v * QSC);
            else Kb[oi] = (__bf16)v;
          }
        }
      } else {
#pragma unroll
        for (int r = 0; r < 4; ++r)
          Y[(size_t)(mrow + r) * 256 + ncol] = acc[fi][fj][r] + b0[ncol];
      }
    }
  }
}

// ============ flash attention: 128q x 128j tiles, 8 waves, exp2-space ============
__launch_bounds__(512, 4)
__global__ void k_flash(const __bf16* __restrict__ Qb, const __bf16* __restrict__ Kb,
                        const __bf16* __restrict__ VT, const float* __restrict__ REL,
                        const __bf16* __restrict__ SUFtab, const __bf16* __restrict__ PREtab,
                        const float* __restrict__ MT, __bf16* __restrict__ Ob) {
  const int bh = blockIdx.y, qt = blockIdx.x, b = bh >> 3;
  const int tid = threadIdx.x, wid = tid >> 6, lane = tid & 63;
  const int l16 = lane & 15, lhi = lane >> 4;

  __shared__ __align__(16) __bf16 kbuf[2][128 * 32];
  __shared__ __align__(16) __bf16 vbuf[2][32 * 128];
  __shared__ __align__(16) __bf16 plds[8][16 * 136];

  const int qrow = qt * 128 + wid * 16 + l16;
  const size_t rg = (size_t)bh * SEQ + qrow;
  const bf16x8 qfrag = *(const bf16x8*)(Qb + rg * HD + lhi * 8);
  const float2 uw = *(const float2*)(REL + rg * 2);
  const float uu = uw.x, ww = uw.y, duw = uu - ww;
  const float duw16 = 16.f * duw;
  const f32x4 duwr = {0.f, duw, 2.f * duw, 3.f * duw};

  const int kj = tid >> 2, kc = tid & 3;
  const __bf16* ksrc = Kb + (size_t)bh * SEQ * HD + (size_t)kj * HD + ((kc ^ ((kj >> 1) & 3)) * 8);
  const int vd = tid >> 4, vc = tid & 15;
  const __bf16* vsrc = VT + ((size_t)bh * HD + vd) * SEQ + ((vc ^ (vd & 7)) * 8);

  f32x4 of0 = {0.f, 0.f, 0.f, 0.f}, of1 = {0.f, 0.f, 0.f, 0.f};
  const f32x4 zero4 = {0.f, 0.f, 0.f, 0.f};
  float m = -3.0e38f, lsum = 0.f;
  __bf16* pl = &plds[wid][0];
  const float* mtp = MT + b * SEQ + lhi * 4;

  GLOAD(ksrc, &kbuf[0][(size_t)tid * 8]);
  GLOAD(vsrc, &vbuf[0][(size_t)tid * 8]);
  __syncthreads();

  for (int t = 0, cur = 0; t < 16; ++t, cur ^= 1) {
    const int jb = t * 128;
    if (t < 15) {
      GLOAD(ksrc + (size_t)(jb + 128) * HD, &kbuf[cur ^ 1][(size_t)tid * 8]);
      GLOAD(vsrc + (jb + 128), &vbuf[cur ^ 1][(size_t)tid * 8]);
    }
    const __bf16* kb = kbuf[cur];
    const __bf16* vb = vbuf[cur];

    f32x4 sf[8];
    __builtin_amdgcn_s_setprio(1);
#pragma unroll
    for (int jt = 0; jt < 8; ++jt) {
      const int row = jt * 16 + l16;
      bf16x8 kf = *(const bf16x8*)(kb + row * 32 + ((lhi ^ ((row >> 1) & 3)) * 8));
      sf[jt] = __builtin_amdgcn_mfma_f32_16x16x32_bf16(kf, qfrag, zero4, 0, 0, 0);
    }
    __builtin_amdgcn_s_setprio(0);

    if (t == 0) {                       // edge: missing-bucket dots + linear corr
      const bf16x8 s0 = *(const bf16x8*)(SUFtab + l16 * HD + lhi * 8);
      const bf16x8 s1 = *(const bf16x8*)(SUFtab + (16 + l16) * HD + lhi * 8);
      sf[0] -= __builtin_amdgcn_mfma_f32_16x16x32_bf16(s0, qfrag, zero4, 0, 0, 0);
      sf[1] -= __builtin_amdgcn_mfma_f32_16x16x32_bf16(s1, qfrag, zero4, 0, 0, 0);
#pragma unroll
      for (int jt = 0; jt < 2; ++jt)
#pragma unroll
        for (int r = 0; r < 4; ++r)
          sf[jt][r] += fmaxf(31.f - (float)(jt * 16 + lhi * 4 + r), 0.f) * uu;
    }
    if (t == 15) {
      const bf16x8 p0 = *(const bf16x8*)(PREtab + l16 * HD + lhi * 8);
      const bf16x8 p1 = *(const bf16x8*)(PREtab + (16 + l16) * HD + lhi * 8);
      sf[6] -= __builtin_amdgcn_mfma_f32_16x16x32_bf16(p0, qfrag, zero4, 0, 0, 0);
      sf[7] -= __builtin_amdgcn_mfma_f32_16x16x32_bf16(p1, qfrag, zero4, 0, 0, 0);
#pragma unroll
      for (int jt = 6; jt < 8; ++jt)
#pragma unroll
        for (int r = 0; r < 4; ++r)
          sf[jt][r] += fmaxf((float)(jb + jt * 16 + lhi * 4 + r) - 2016.f, 0.f) * ww;
    }

    f32x4 lin = duwr + (float)(jb + lhi * 4) * duw;
    float tmax = -3.0e38f;
#pragma unroll
    for (int jt = 0; jt < 8; ++jt) {
      f32x4 mt4 = *(const f32x4*)(mtp + jb + jt * 16);
      f32x4 s = sf[jt] + lin + mt4;
      lin += duw16;
      sf[jt] = s;
      tmax = fmaxf(tmax, fmaxf(fmaxf(s.x, s.y), fmaxf(s.z, s.w)));
    }
    tmax = fmaxf(tmax, __shfl_xor(tmax, 16));
    tmax = fmaxf(tmax, __shfl_xor(tmax, 32));

    const float mn = fmaxf(m, tmax);
    const float c = __builtin_amdgcn_exp2f(m - mn);
    m = mn;
    of0 *= c; of1 *= c;
    float csum = 0.f;
#pragma unroll
    for (int jt = 0; jt < 8; ++jt) {
      f32x4 e;
#pragma unroll
      for (int r = 0; r < 4; ++r) e[r] = __builtin_amdgcn_exp2f(sf[jt][r] - m);
      csum += (e.x + e.y) + (e.z + e.w);
      union { __bf16 h4[4]; uint2 u; } pk;
#pragma unroll
      for (int r = 0; r < 4; ++r) pk.h4[r] = (__bf16)e[r];
      *(uint2*)(pl + l16 * 136 + jt * 16 + lhi * 4) = pk.u;
    }
    csum += __shfl_xor(csum, 16);
    csum += __shfl_xor(csum, 32);
    lsum = lsum * c + csum;

    __builtin_amdgcn_s_setprio(1);
#pragma unroll
    for (int kt = 0; kt < 4; ++kt) {
      bf16x8 pf = *(const bf16x8*)(pl + l16 * 136 + kt * 32 + lhi * 8);
      bf16x8 v0 = *(const bf16x8*)(vb + l16 * 128 + (((kt * 4 + lhi) ^ (l16 & 7)) * 8));
      bf16x8 v1 = *(const bf16x8*)(vb + (16 + l16) * 128 + (((kt * 4 + lhi) ^ (l16 & 7)) * 8));
      of0 = __builtin_amdgcn_mfma_f32_16x16x32_bf16(v0, pf, of0, 0, 0, 0);
      of1 = __builtin_amdgcn_mfma_f32_16x16x32_bf16(v1, pf, of1, 0, 0, 0);
    }
    __builtin_amdgcn_s_setprio(0);
    __syncthreads();
  }

  const float inv = 1.0f / lsum;
  union { __bf16 h4[4]; uint2 u; } o0, o1;
#pragma unroll
  for (int r = 0; r < 4; ++r) {
    o0.h4[r] = (__bf16)(of0[r] * inv);
    o1.h4[r] = (__bf16)(of1[r] * inv);
  }
  *(uint2*)(Ob + rg * HD + lhi * 4) = o0.u;
  *(uint2*)(Ob + rg * HD + 16 + lhi * 4) = o1.u;
}

// ============ launch ============
extern "C" void kernel_launch(void* const* d_in, const int* in_sizes, int n_in,
                              void* d_out, int out_size, void* d_ws, size_t ws_size,
                              hipStream_t stream) {
  (void)in_sizes; (void)n_in; (void)out_size; (void)ws_size;
  const float* query = (const float*)d_in[0];
  const float* mask  = (const float*)d_in[1];
  const float* Wq = (const float*)d_in[2];
  const float* bq = (const float*)d_in[3];
  const float* Wk = (const float*)d_in[4];
  const float* bk = (const float*)d_in[5];
  const float* Wv = (const float*)d_in[6];
  const float* bv = (const float*)d_in[7];
  const float* Wo = (const float*)d_in[8];
  const float* bo = (const float*)d_in[9];
  const float* tbl = (const float*)d_in[10];
  float* out = (float*)d_out;
  char* ws = (char*)d_ws;

  const size_t MB = 1024ull * 1024;
  __bf16* Xb    = (__bf16*)(ws);                          // 4 MB
  __bf16* Wt    = (__bf16*)(ws + 4 * MB);                 // 384 KB
  __bf16* WoT   = (__bf16*)(ws + 4 * MB + 393216);        // 128 KB
  __bf16* SUFt  = (__bf16*)(ws + 4 * MB + 524288);        // 2 KB
  __bf16* PREt  = (__bf16*)(ws + 4 * MB + 526336);        // 2 KB
  float*  WV2T  = (float*) (ws + 4 * MB + 528384);        // 16 KB
  float*  cbv   = (float*) (ws + 4 * MB + 544768);        // 64 B
  float*  MT    = (float*) (ws + 4 * MB + 544832);        // 32 KB
  float*  REL   = (float*) (ws + 5 * MB);                 // 512 KB
  __bf16* Qb    = (__bf16*)(ws + 6 * MB);                 // 4 MB
  __bf16* Kb    = (__bf16*)(ws + 10 * MB);                // 4 MB
  __bf16* VT    = (__bf16*)(ws + 14 * MB);                // 4 MB
  __bf16* Ob    = (__bf16*)(ws + 18 * MB);                // 4 MB

  k_prep<<<1171, 256, 0, stream>>>(query, mask, Wq, Wk, Wv, Wo, bq, tbl,
                                   Xb, Wt, WoT, MT, SUFt, PREt, WV2T, cbv);
  k_rel<<<256, 256, 0, stream>>>(query, WV2T, cbv, REL);
  k_gemm<0><<<dim3(64, 6), 256, 0, stream>>>(Xb, Wt, bq, bk, bv, Qb, Kb, VT, nullptr);
  k_flash<<<dim3(16, 32), 512, 0, stream>>>(Qb, Kb, VT, REL, SUFt, PREt, MT, Ob);
  k_gemm<1><<<dim3(64, 4), 256, 0, stream>>>(Ob, WoT, bo, nullptr, nullptr,
                                             nullptr, nullptr, nullptr, out);
}

// Round 5
// 89.648 us; speedup vs baseline: 3.6341x; 1.1975x over previous
//
#include <hip/hip_runtime.h>
#include <hip/hip_bf16.h>
#include <math.h>

#define NH 8
#define HD 32
#define SEQ 2048
#define DM 256
#define SCALE 0.17677669529663687f      // 1/sqrt(32)
#define INV_SCALE 5.656854249492381f    // sqrt(32)
#define LOG2E 1.4426950408889634f
#define QSC (SCALE * LOG2E)
#define MNEG (-1e9f * LOG2E)

typedef float f32x4 __attribute__((ext_vector_type(4)));
typedef __bf16 bf16x8 __attribute__((ext_vector_type(8)));

#define GLOAD(g, l) __builtin_amdgcn_global_load_lds( \
    (const __attribute__((address_space(1))) void*)(g), \
    (__attribute__((address_space(3))) void*)(l), 16, 0, 0)

// ============ prep: X->bf16, LDS-tiled W transposes, MT+flag, SUFn/PREn, WV2T, cb ============
__global__ void k_prep(const float* __restrict__ query, const float* __restrict__ mask,
                       const float* __restrict__ Wq, const float* __restrict__ Wk,
                       const float* __restrict__ Wv, const float* __restrict__ Wo,
                       const float* __restrict__ bq, const float* __restrict__ tbl,
                       __bf16* __restrict__ Xb, __bf16* __restrict__ Wt,
                       __bf16* __restrict__ WoT, float* __restrict__ MT,
                       __bf16* __restrict__ SUFn, __bf16* __restrict__ PREn,
                       float* __restrict__ WV2T, float* __restrict__ cb,
                       int* __restrict__ MFLAG) {
  const int blk = blockIdx.x, tid = threadIdx.x;
  __shared__ float ts[64][65];
  __shared__ int okl;
  if (blk < 1024) {                      // X f32 -> bf16
    size_t i = (size_t)blk * 2048 + (size_t)tid * 8;
    float4 a = *(const float4*)(query + i);
    float4 b4 = *(const float4*)(query + i + 4);
    union { __bf16 h[8]; bf16x8 v; } o;
    o.h[0] = (__bf16)a.x;  o.h[1] = (__bf16)a.y;
    o.h[2] = (__bf16)a.z;  o.h[3] = (__bf16)a.w;
    o.h[4] = (__bf16)b4.x; o.h[5] = (__bf16)b4.y;
    o.h[6] = (__bf16)b4.z; o.h[7] = (__bf16)b4.w;
    *(bf16x8*)(Xb + i) = o.v;
  } else if (blk < 1088) {               // LDS-tiled transposes (48 QKV + 16 Wo)
    const int idx = blk - 1024;
    const float* W;
    __bf16* dst;
    int tile;
    if (idx < 48) {
      int which = idx >> 4;
      W = which == 0 ? Wq : (which == 1 ? Wk : Wv);
      dst = Wt + which * 65536;
      tile = idx & 15;
    } else {
      W = Wo; dst = WoT; tile = idx - 48;
    }
    const int tr = (tile >> 2) * 64, tc = (tile & 3) * 64;
#pragma unroll
    for (int p = 0; p < 4; ++p) {
      int row = p * 16 + (tid >> 4);
      int col = (tid & 15) * 4;
      float4 v = *(const float4*)(W + (size_t)(tr + row) * 256 + tc + col);
      ts[row][col] = v.x; ts[row][col + 1] = v.y;
      ts[row][col + 2] = v.z; ts[row][col + 3] = v.w;
    }
    __syncthreads();
#pragma unroll
    for (int p = 0; p < 2; ++p) {
      int n = p * 32 + (tid >> 3);
      int kb = (tid & 7) * 8;
      union { __bf16 h[8]; bf16x8 v; } o;
#pragma unroll
      for (int e = 0; e < 8; ++e) o.h[e] = (__bf16)ts[kb + e][n];
      *(bf16x8*)(dst + (size_t)(tc + n) * 256 + tr + kb) = o.v;
    }
  } else if (blk == 1088) {              // MT (log2e-folded) + mask-ones flag
    if (tid == 0) okl = 1;
    __syncthreads();
    bool ok = true;
    for (int i = tid; i < 4 * SEQ; i += 256) {
      float mv = mask[i];
      MT[i] = (1.0f - mv) * MNEG;
      ok &= (mv == 1.0f);
    }
    if (!ok) atomicAnd(&okl, 0);
    __syncthreads();
    if (tid == 0) MFLAG[0] = okl;
  } else if (blk == 1089) {              // SUFn/PREn (negated prefix sums, /SCALE)
    for (int idx = tid; idx < 1024; idx += 256) {
      int j = idx >> 5, d = idx & 31;
      float s = 0.f;
      for (int u = j + 33; u <= 63; ++u) s += tbl[u * 32 + d];
      SUFn[idx] = (__bf16)(-s * INV_SCALE);
    }
    for (int idx = tid; idx < 1024; idx += 256) {
      int jj = idx >> 5, d = idx & 31;
      float s = 0.f;
      for (int u = 1; u <= jj; ++u) s += tbl[u * 32 + d];
      PREn[idx] = (__bf16)(-s * INV_SCALE);
    }
  } else if (blk < 1106) {               // WV2T[16][256] (x log2e)
    int tg = (blk - 1090) * 256 + tid;
    int hv = tg >> 8, k = tg & 255;
    const float* T = tbl + ((hv & 1) ? 0 : 64 * 32);
    const float* w = Wq + (size_t)k * 256 + (hv >> 1) * 32;
    float acc = 0.f;
#pragma unroll
    for (int d = 0; d < 32; ++d) acc = fmaf(w[d], T[d], acc);
    WV2T[hv * 256 + k] = acc * LOG2E;
  } else {                               // cb[16]
    if (tid < 16) {
      const float* T = tbl + ((tid & 1) ? 0 : 64 * 32);
      float a = 0.f;
#pragma unroll
      for (int d = 0; d < 32; ++d) a = fmaf(bq[(tid >> 1) * 32 + d], T[d], a);
      cb[tid] = a * LOG2E;
    }
  }
}

// ============ REL = (X @ WV2T^T + cb), LDS-staged (f32 exact) ============
__launch_bounds__(256)
__global__ void k_rel(const float* __restrict__ X, const float* __restrict__ WV2T,
                      const float* __restrict__ cb, float* __restrict__ REL) {
  __shared__ float Xs[32][260];
  __shared__ float Ws[16][260];
  const int tid = threadIdx.x;
  const size_t base = (size_t)blockIdx.x * 32 * 256;
#pragma unroll
  for (int p = 0; p < 8; ++p) {
    int idx = p * 1024 + tid * 4;
    float4 v = *(const float4*)(X + base + idx);
    *(float4*)&Xs[idx >> 8][idx & 255] = v;
  }
#pragma unroll
  for (int p = 0; p < 4; ++p) {
    int idx = p * 1024 + tid * 4;
    float4 v = *(const float4*)(WV2T + idx);
    *(float4*)&Ws[idx >> 8][idx & 255] = v;
  }
  __syncthreads();
  const int hv = tid & 15, rl = tid >> 4;
  float a0 = cb[hv], a1 = a0;
  const float* xs0 = &Xs[rl][0];
  const float* xs1 = &Xs[rl + 16][0];
  const float* wsp = &Ws[hv][0];
#pragma unroll 8
  for (int k = 0; k < 256; ++k) {
    float w = wsp[k];
    a0 = fmaf(xs0[k], w, a0);
    a1 = fmaf(xs1[k], w, a1);
  }
  const int row0 = blockIdx.x * 32 + rl;
  const int h = hv >> 1, v = hv & 1;
  const int b0i = row0 >> 11, s0 = row0 & 2047;
  REL[((size_t)(b0i * NH + h) * SEQ + s0) * 2 + v] = a0;
  const int r1 = row0 + 16;
  const int b1i = r1 >> 11, s1 = r1 & 2047;
  REL[((size_t)(b1i * NH + h) * SEQ + s1) * 2 + v] = a1;
}

// ============ bf16 MFMA GEMM ============
template <int MODE>
__launch_bounds__(256)
__global__ void k_gemm(const __bf16* __restrict__ A, const __bf16* __restrict__ Bt,
                       const float* __restrict__ b0, const float* __restrict__ b1,
                       const float* __restrict__ b2,
                       __bf16* __restrict__ Qb, __bf16* __restrict__ Kb,
                       __bf16* __restrict__ VTout, float* __restrict__ Y) {
  constexpr int BN = (MODE == 0) ? 128 : 64;
  constexpr int NFJ = BN / 32;
  __shared__ __align__(16) __bf16 As[128 * 64];
  __shared__ __align__(16) __bf16 Bs[BN * 64];
  const int tid = threadIdx.x, lane = tid & 63, wid = tid >> 6;
  const int l16 = lane & 15, lhi = lane >> 4;
  const int wr = wid >> 1, wc = wid & 1;
  const int m0 = blockIdx.x * 128, n0 = blockIdx.y * BN;

  f32x4 acc[4][NFJ];
#pragma unroll
  for (int i = 0; i < 4; ++i)
#pragma unroll
    for (int j = 0; j < NFJ; ++j) acc[i][j] = (f32x4){0.f, 0.f, 0.f, 0.f};

  for (int k0 = 0; k0 < 256; k0 += 64) {
    __syncthreads();
#pragma unroll
    for (int cc = 0; cc < 4; ++cc) {
      int cl = tid + cc * 256;
      int row = cl >> 3, kc = cl & 7;
      int k = k0 + ((kc ^ (row & 7)) * 8);
      const __bf16* src;
      if constexpr (MODE == 0) {
        src = A + (size_t)(m0 + row) * 256 + k;
      } else {
        int r = m0 + row, bb = r >> 11, s = r & 2047, h = k >> 5, dh = k & 31;
        src = A + ((size_t)(bb * NH + h) * SEQ + s) * HD + dh;
      }
      GLOAD(src, (__bf16*)As + (size_t)cl * 8);
    }
#pragma unroll
    for (int cc = 0; cc < NFJ; ++cc) {
      int cl = tid + cc * 256;
      int row = cl >> 3, kc = cl & 7;
      int k = k0 + ((kc ^ (row & 7)) * 8);
      GLOAD(Bt + (size_t)(n0 + row) * 256 + k, (__bf16*)Bs + (size_t)cl * 8);
    }
    __syncthreads();
#pragma unroll
    for (int kk = 0; kk < 64; kk += 32) {
      bf16x8 af[4], bfr[NFJ];
#pragma unroll
      for (int fi = 0; fi < 4; ++fi) {
        int row = wr * 64 + fi * 16 + l16;
        af[fi] = *(const bf16x8*)(As + row * 64 + ((((kk >> 3) + lhi) ^ (row & 7)) * 8));
      }
#pragma unroll
      for (int fj = 0; fj < NFJ; ++fj) {
        int row = wc * (BN / 2) + fj * 16 + l16;
        bfr[fj] = *(const bf16x8*)(Bs + row * 64 + ((((kk >> 3) + lhi) ^ (row & 7)) * 8));
      }
#pragma unroll
      for (int fi = 0; fi < 4; ++fi)
#pragma unroll
        for (int fj = 0; fj < NFJ; ++fj)
          acc[fi][fj] = __builtin_amdgcn_mfma_f32_16x16x32_bf16(af[fi], bfr[fj], acc[fi][fj], 0, 0, 0);
    }
  }
#pragma unroll
  for (int fi = 0; fi < 4; ++fi) {
#pragma unroll
    for (int fj = 0; fj < NFJ; ++fj) {
      int mrow = m0 + wr * 64 + fi * 16 + lhi * 4;
      int ncol = n0 + wc * (BN / 2) + fj * 16 + l16;
      if constexpr (MODE == 0) {
        int which = ncol >> 8, nw = ncol & 255, h = nw >> 5, dh = nw & 31;
        int bb = mrow >> 11, s0 = mrow & 2047;
        if (which == 2) {
          union { __bf16 h4[4]; uint2 u; } o;
#pragma unroll
          for (int r = 0; r < 4; ++r) o.h4[r] = (__bf16)(acc[fi][fj][r] + b2[nw]);
          *(uint2*)(VTout + ((size_t)(bb * NH + h) * HD + dh) * SEQ + s0) = o.u;
        } else {
          const float* bias = which == 0 ? b0 : b1;
#pragma unroll
          for (int r = 0; r < 4; ++r) {
            float v = acc[fi][fj][r] + bias[nw];
            size_t oi = ((size_t)(bb * NH + h) * SEQ + (s0 + r)) * HD + dh;
            if (which == 0) Qb[oi] = (__bf16)(v * QSC);
            else Kb[oi] = (__bf16)v;
          }
        }
      } else {
#pragma unroll
        for (int r = 0; r < 4; ++r)
          Y[(size_t)(mrow + r) * 256 + ncol] = acc[fi][fj][r] + b0[ncol];
      }
    }
  }
}

// ============ flash: online-max, C-folded lin/edges, ones-MFMA lsum, swizzled P ============
__launch_bounds__(512, 4)
__global__ void k_flash(const __bf16* __restrict__ Qb, const __bf16* __restrict__ Kb,
                        const __bf16* __restrict__ VT, const float* __restrict__ REL,
                        const __bf16* __restrict__ SUFn, const __bf16* __restrict__ PREn,
                        const float* __restrict__ MT, const int* __restrict__ MFLAG,
                        __bf16* __restrict__ Ob) {
  const int bh = blockIdx.y, qt = blockIdx.x, b = bh >> 3;
  const int tid = threadIdx.x, wid = tid >> 6, lane = tid & 63;
  const int l16 = lane & 15, lhi = lane >> 4;

  __shared__ __align__(16) __bf16 kbuf[2][128 * 32];   // 16 KB
  __shared__ __align__(16) __bf16 vbuf[2][32 * 128];   // 16 KB
  __shared__ __align__(16) __bf16 plds[8][16 * 128];   // 32 KB, 16B-XOR swizzled

  const int qrow = qt * 128 + wid * 16 + l16;
  const size_t rg = (size_t)bh * SEQ + qrow;
  const bf16x8 qfrag = *(const bf16x8*)(Qb + rg * HD + lhi * 8);
  const float2 uw = *(const float2*)(REL + rg * 2);
  const float uu = uw.x, ww = uw.y, duw = uu - ww;
  const float duw16 = 16.f * duw;
  const f32x4 duwr = {0.f, duw, 2.f * duw, 3.f * duw};
  const int flag = MFLAG[0];

  const int kj = tid >> 2, kc = tid & 3;
  const __bf16* ksrc = Kb + (size_t)bh * SEQ * HD + (size_t)kj * HD + ((kc ^ ((kj >> 1) & 3)) * 8);
  const int vd = tid >> 4, vc = tid & 15;
  const __bf16* vsrc = VT + ((size_t)bh * HD + vd) * SEQ + ((vc ^ (vd & 7)) * 8);

  f32x4 of0 = {0.f, 0.f, 0.f, 0.f}, of1 = {0.f, 0.f, 0.f, 0.f}, of2 = {0.f, 0.f, 0.f, 0.f};
  const f32x4 zero4 = {0.f, 0.f, 0.f, 0.f}; (void)zero4;
  bf16x8 ones;
#pragma unroll
  for (int e = 0; e < 8; ++e) ones[e] = (__bf16)1.0f;
  float m = -3.0e38f;
  __bf16* pl = &plds[wid][0];
  const float* mtp = MT + b * SEQ + lhi * 4;

  GLOAD(ksrc, &kbuf[0][(size_t)tid * 8]);
  GLOAD(vsrc, &vbuf[0][(size_t)tid * 8]);
  __syncthreads();

  for (int t = 0, cur = 0; t < 16; ++t, cur ^= 1) {
    const int jb = t * 128;
    if (t < 15) {
      GLOAD(ksrc + (size_t)(jb + 128) * HD, &kbuf[cur ^ 1][(size_t)tid * 8]);
      GLOAD(vsrc + (jb + 128), &vbuf[cur ^ 1][(size_t)tid * 8]);
    }
    const __bf16* kb = kbuf[cur];
    const __bf16* vb = vbuf[cur];

    // QK^T swapped; linear rel term folded into the MFMA C-operand
    f32x4 lin = duwr + (float)(jb + lhi * 4) * duw;
    f32x4 sf[8];
    __builtin_amdgcn_s_setprio(1);
#pragma unroll
    for (int jt = 0; jt < 8; ++jt) {
      const int row = jt * 16 + l16;
      bf16x8 kf = *(const bf16x8*)(kb + row * 32 + ((lhi ^ ((row >> 1) & 3)) * 8));
      sf[jt] = __builtin_amdgcn_mfma_f32_16x16x32_bf16(kf, qfrag, lin, 0, 0, 0);
      lin += duw16;
    }
    __builtin_amdgcn_s_setprio(0);

    if (t == 0) {                       // edge: negated-bucket dots via C + linear corr
      const bf16x8 s0 = *(const bf16x8*)(SUFn + l16 * HD + lhi * 8);
      const bf16x8 s1 = *(const bf16x8*)(SUFn + (16 + l16) * HD + lhi * 8);
      sf[0] = __builtin_amdgcn_mfma_f32_16x16x32_bf16(s0, qfrag, sf[0], 0, 0, 0);
      sf[1] = __builtin_amdgcn_mfma_f32_16x16x32_bf16(s1, qfrag, sf[1], 0, 0, 0);
#pragma unroll
      for (int jt = 0; jt < 2; ++jt)
#pragma unroll
        for (int r = 0; r < 4; ++r)
          sf[jt][r] += fmaxf(31.f - (float)(jt * 16 + lhi * 4 + r), 0.f) * uu;
    }
    if (t == 15) {
      const bf16x8 p0 = *(const bf16x8*)(PREn + l16 * HD + lhi * 8);
      const bf16x8 p1 = *(const bf16x8*)(PREn + (16 + l16) * HD + lhi * 8);
      sf[6] = __builtin_amdgcn_mfma_f32_16x16x32_bf16(p0, qfrag, sf[6], 0, 0, 0);
      sf[7] = __builtin_amdgcn_mfma_f32_16x16x32_bf16(p1, qfrag, sf[7], 0, 0, 0);
#pragma unroll
      for (int jt = 6; jt < 8; ++jt)
#pragma unroll
        for (int r = 0; r < 4; ++r)
          sf[jt][r] += fmaxf((float)(1920 + jt * 16 + lhi * 4 + r) - 2016.f, 0.f) * ww;
    }
    if (!flag) {
#pragma unroll
      for (int jt = 0; jt < 8; ++jt)
        sf[jt] += *(const f32x4*)(mtp + jb + jt * 16);
    }

    // online max
    float tmax = -3.0e38f;
#pragma unroll
    for (int jt = 0; jt < 8; ++jt)
      tmax = fmaxf(tmax, fmaxf(fmaxf(sf[jt].x, sf[jt].y), fmaxf(sf[jt].z, sf[jt].w)));
    tmax = fmaxf(tmax, __shfl_xor(tmax, 16));
    tmax = fmaxf(tmax, __shfl_xor(tmax, 32));
    const float mn = fmaxf(m, tmax);
    const float c = __builtin_amdgcn_exp2f(m - mn);
    m = mn;
    of0 *= c; of1 *= c; of2 *= c;

    // exp2 + pack into swizzled P-LDS
#pragma unroll
    for (int jt = 0; jt < 8; ++jt) {
      union { __bf16 h4[4]; uint2 u; } pk;
#pragma unroll
      for (int r = 0; r < 4; ++r)
        pk.h4[r] = (__bf16)__builtin_amdgcn_exp2f(sf[jt][r] - m);
      const int blk16 = ((jt * 2 + (lhi >> 1)) ^ (l16 & 7));
      *(uint2*)(pl + l16 * 128 + blk16 * 8 + (lhi & 1) * 4) = pk.u;
    }

    // PV + ones-row lsum (all on matrix pipe)
    __builtin_amdgcn_s_setprio(1);
#pragma unroll
    for (int kt = 0; kt < 4; ++kt) {
      const int pblk = (kt * 4 + lhi) ^ (l16 & 7);
      bf16x8 pf = *(const bf16x8*)(pl + l16 * 128 + pblk * 8);
      bf16x8 v0 = *(const bf16x8*)(vb + l16 * 128 + (((kt * 4 + lhi) ^ (l16 & 7)) * 8));
      bf16x8 v1 = *(const bf16x8*)(vb + (16 + l16) * 128 + (((kt * 4 + lhi) ^ (l16 & 7)) * 8));
      of0 = __builtin_amdgcn_mfma_f32_16x16x32_bf16(v0, pf, of0, 0, 0, 0);
      of1 = __builtin_amdgcn_mfma_f32_16x16x32_bf16(v1, pf, of1, 0, 0, 0);
      of2 = __builtin_amdgcn_mfma_f32_16x16x32_bf16(ones, pf, of2, 0, 0, 0);
    }
    __builtin_amdgcn_s_setprio(0);
    __syncthreads();
  }

  const float inv = 1.0f / of2[0];
  union { __bf16 h4[4]; uint2 u; } o0, o1;
#pragma unroll
  for (int r = 0; r < 4; ++r) {
    o0.h4[r] = (__bf16)(of0[r] * inv);
    o1.h4[r] = (__bf16)(of1[r] * inv);
  }
  *(uint2*)(Ob + rg * HD + lhi * 4) = o0.u;
  *(uint2*)(Ob + rg * HD + 16 + lhi * 4) = o1.u;
}

// ============ launch ============
extern "C" void kernel_launch(void* const* d_in, const int* in_sizes, int n_in,
                              void* d_out, int out_size, void* d_ws, size_t ws_size,
                              hipStream_t stream) {
  (void)in_sizes; (void)n_in; (void)out_size; (void)ws_size;
  const float* query = (const float*)d_in[0];
  const float* mask  = (const float*)d_in[1];
  const float* Wq = (const float*)d_in[2];
  const float* bq = (const float*)d_in[3];
  const float* Wk = (const float*)d_in[4];
  const float* bk = (const float*)d_in[5];
  const float* Wv = (const float*)d_in[6];
  const float* bv = (const float*)d_in[7];
  const float* Wo = (const float*)d_in[8];
  const float* bo = (const float*)d_in[9];
  const float* tbl = (const float*)d_in[10];
  float* out = (float*)d_out;
  char* ws = (char*)d_ws;

  const size_t MB = 1024ull * 1024;
  __bf16* Xb    = (__bf16*)(ws);                          // 4 MB
  __bf16* Wt    = (__bf16*)(ws + 4 * MB);                 // 384 KB
  __bf16* WoT   = (__bf16*)(ws + 4 * MB + 393216);        // 128 KB
  __bf16* SUFn  = (__bf16*)(ws + 4 * MB + 524288);        // 2 KB
  __bf16* PREn  = (__bf16*)(ws + 4 * MB + 526336);        // 2 KB
  float*  WV2T  = (float*) (ws + 4 * MB + 528384);        // 16 KB
  float*  cbv   = (float*) (ws + 4 * MB + 544768);        // 64 B
  float*  MT    = (float*) (ws + 4 * MB + 544832);        // 32 KB
  int*    MFLAG = (int*)   (ws + 4 * MB + 577600);        // 4 B
  float*  REL   = (float*) (ws + 5 * MB);                 // 512 KB
  __bf16* Qb    = (__bf16*)(ws + 6 * MB);                 // 4 MB
  __bf16* Kb    = (__bf16*)(ws + 10 * MB);                // 4 MB
  __bf16* VT    = (__bf16*)(ws + 14 * MB);                // 4 MB
  __bf16* Ob    = (__bf16*)(ws + 18 * MB);                // 4 MB

  k_prep<<<1107, 256, 0, stream>>>(query, mask, Wq, Wk, Wv, Wo, bq, tbl,
                                   Xb, Wt, WoT, MT, SUFn, PREn, WV2T, cbv, MFLAG);
  k_rel<<<256, 256, 0, stream>>>(query, WV2T, cbv, REL);
  k_gemm<0><<<dim3(64, 6), 256, 0, stream>>>(Xb, Wt, bq, bk, bv, Qb, Kb, VT, nullptr);
  k_flash<<<dim3(16, 32), 512, 0, stream>>>(Qb, Kb, VT, REL, SUFn, PREn, MT, MFLAG, Ob);
  k_gemm<1><<<dim3(64, 4), 256, 0, stream>>>(Ob, WoT, bo, nullptr, nullptr,
                                             nullptr, nullptr, nullptr, out);
}